// Round 13
// baseline (129.762 us; speedup 1.0000x reference)
//
#include <hip/hip_runtime.h>

#define NROWS 8192
#define DDIM  256
#define KSPLIT 4
#define BM 128
#define BK 64
#define NT (NROWS / KSPLIT / BK)   // 32 tiles per split

typedef __bf16 bf16x8 __attribute__((ext_vector_type(8)));
typedef float  f32x4  __attribute__((ext_vector_type(4)));
typedef float  f32x16 __attribute__((ext_vector_type(16)));

typedef __attribute__((address_space(1))) unsigned int uint_gas;
typedef __attribute__((address_space(3))) unsigned int uint_las;

__device__ __forceinline__ void gload_lds16(const void* g, void* l) {
  __builtin_amdgcn_global_load_lds((const uint_gas*)g, (uint_las*)l, 16, 0, 0);
}

__device__ __forceinline__ unsigned int f2bf_bits(float f) {
  union { float f; unsigned int u; } v; v.f = f;
  unsigned int r = v.u + 0x7FFFu + ((v.u >> 16) & 1u);
  return r >> 16;
}
__device__ __forceinline__ float bf2f(unsigned int b) {
  union { unsigned int u; float f; } v; v.u = b << 16;
  return v.f;
}
__device__ __forceinline__ unsigned int pack2bf(float a, float b) {
  union { unsigned int u; __bf16 h[2]; } p;
  p.h[0] = (__bf16)a; p.h[1] = (__bf16)b;
  return p.u;
}
__device__ __forceinline__ unsigned short f2h_bits(float f) {
  union { _Float16 h; unsigned short u; } c; c.h = (_Float16)f;
  return c.u;
}
__device__ __forceinline__ float h2f(unsigned short u) {
  union { unsigned short u; _Float16 h; } c; c.u = u;
  return (float)c.h;
}

// ---------------- kernel 0: fp32 -> bf16, MFMA-fragment-order packing ----------------
// xpack: fid = (rt*8 + ks)*64 + l  -> x[rt*16 + (l&15)][ks*32 + (l>>4)*8 .. +8]
// Wpack: fid = ((out*16+ct)*8 + ks)*64 + l -> W_out[ct*16+(l&15)][ks*32+(l>>4)*8 .. +8]
#define NXFRAG (512 * 8 * 64)        // 262144
#define NWFRAG (3 * 16 * 8 * 64)     // 24576
__global__ __launch_bounds__(256) void convert_kernel(
    const float* __restrict__ x, const float* __restrict__ wq,
    const float* __restrict__ wk, const float* __restrict__ wv,
    unsigned short* __restrict__ xp, unsigned short* __restrict__ Wp)
{
  int tid = blockIdx.x * 256 + threadIdx.x;
  const float* src;
  unsigned short* dst;
  int row, col;
  if (tid < NXFRAG) {
    int l = tid & 63, ks = (tid >> 6) & 7, rt = tid >> 9;
    src = x; dst = xp + (size_t)tid * 8;
    row = rt * 16 + (l & 15); col = ks * 32 + (l >> 4) * 8;
  } else {
    int fid = tid - NXFRAG;
    if (fid >= NWFRAG) return;
    int l = fid & 63, ks = (fid >> 6) & 7, ct = (fid >> 9) & 15, out = fid >> 13;
    src = (out == 0) ? wq : (out == 1) ? wk : wv;
    dst = Wp + (size_t)fid * 8;
    row = ct * 16 + (l & 15); col = ks * 32 + (l >> 4) * 8;
  }
  const float* p = src + (size_t)row * DDIM + col;
  float4 f0 = *(const float4*)p;
  float4 f1 = *(const float4*)(p + 4);
  ushort4 o0, o1;
  o0.x = (unsigned short)f2bf_bits(f0.x); o0.y = (unsigned short)f2bf_bits(f0.y);
  o0.z = (unsigned short)f2bf_bits(f0.z); o0.w = (unsigned short)f2bf_bits(f0.w);
  o1.x = (unsigned short)f2bf_bits(f1.x); o1.y = (unsigned short)f2bf_bits(f1.y);
  o1.z = (unsigned short)f2bf_bits(f1.z); o1.w = (unsigned short)f2bf_bits(f1.w);
  *(ushort4*)dst = o0;
  *(ushort4*)(dst + 4) = o1;
}

// ---------------- kernel 1: QKV projections + L2 norm + vT ----------------
// grid = 384: out = bid/128 (0=q,1=k,2=v), mb = bid%128 (64-row slab)
// v is ONLY emitted as vT (row-major vb dropped — combine no longer needs it).
__global__ __launch_bounds__(256) void qkv_kernel(
    const float* __restrict__ bq, const float* __restrict__ bk, const float* __restrict__ bv,
    const unsigned short* __restrict__ xp, const unsigned short* __restrict__ Wp,
    unsigned short* __restrict__ qb, unsigned short* __restrict__ kb,
    unsigned short* __restrict__ vT)
{
  __shared__ unsigned short vstage[DDIM * 72];
  const int t = threadIdx.x;
  const int w = t >> 6, l = t & 63;
  const int c = l & 15, g = l >> 4;
  const int out = blockIdx.x / 128;
  const int mb  = blockIdx.x % 128;
  const int row0 = mb * 64;
  const int rw = row0 + w * 16;
  const int rt = mb * 4 + w;           // global 16-row tile id

  bf16x8 a[8];
  #pragma unroll
  for (int ks = 0; ks < 8; ks++)
    a[ks] = *(const bf16x8*)(xp + ((size_t)(rt * 8 + ks) * 64 + l) * 8);

  const float* bias = (out == 0) ? bq : (out == 1) ? bk : bv;
  f32x4 vals[16];
  #pragma unroll
  for (int ct = 0; ct < 16; ct++) {
    f32x4 acc = {0.f, 0.f, 0.f, 0.f};
    #pragma unroll
    for (int ks = 0; ks < 8; ks++) {
      bf16x8 b = *(const bf16x8*)(Wp + ((size_t)((out * 16 + ct) * 8 + ks) * 64 + l) * 8);
      acc = __builtin_amdgcn_mfma_f32_16x16x32_bf16(a[ks], b, acc, 0, 0, 0);
    }
    float bias_v = bias[ct * 16 + c];
    #pragma unroll
    for (int r = 0; r < 4; r++) acc[r] += bias_v;
    vals[ct] = acc;
  }
  if (out < 2) {   // L2 normalize rows (q, k)
    #pragma unroll
    for (int r = 0; r < 4; r++) {
      float ss = 0.f;
      #pragma unroll
      for (int ct = 0; ct < 16; ct++) ss += vals[ct][r] * vals[ct][r];
      ss += __shfl_xor(ss, 1); ss += __shfl_xor(ss, 2);
      ss += __shfl_xor(ss, 4); ss += __shfl_xor(ss, 8);
      float inv = 1.f / fmaxf(sqrtf(ss), 1e-12f);
      #pragma unroll
      for (int ct = 0; ct < 16; ct++) vals[ct][r] *= inv;
    }
    unsigned short* dst = (out == 0) ? qb : kb;
    #pragma unroll
    for (int ct = 0; ct < 16; ct++) {
      #pragma unroll
      for (int r = 0; r < 4; r++) {
        unsigned int bits = f2bf_bits(vals[ct][r]);
        unsigned int ob = (unsigned int)__shfl_xor((int)bits, 1);
        if (!(l & 1))
          *(unsigned int*)(dst + (size_t)(rw + g * 4 + r) * DDIM + ct * 16 + c) =
              bits | (ob << 16);
      }
    }
  } else {
    #pragma unroll
    for (int ct = 0; ct < 16; ct++)
      #pragma unroll
      for (int r = 0; r < 4; r++)
        vstage[(ct * 16 + c) * 72 + (w * 16 + g * 4 + r)] =
            (unsigned short)f2bf_bits(vals[ct][r]);
    __syncthreads();
    #pragma unroll
    for (int p = 0; p < 8; p++) {
      int dd = (t >> 3) + p * 32;
      int ch = t & 7;
      *(uint4*)(vT + (size_t)dd * NROWS + row0 + ch * 8) =
          *(const uint4*)(vstage + dd * 72 + ch * 8);
    }
  }
}

// ---------------- kernel 2: fused relu-attention, producer-consumer waves ----------------
// 1024 threads = 16 waves @ 4/SIMD. Waves 0-7 (S): hold qa, compute S^T=K.Q^T from
// kbuf, ZERO THE DIAGONAL, pack P->Pb[cur], stage K, track den (diag excluded).
// Waves 8-15 (PV): compute P(it-1).V(it-1), stage V, write nump.
__global__ __launch_bounds__(1024, 4) void attn_kernel(
    const unsigned short* __restrict__ qb, const unsigned short* __restrict__ kb,
    const unsigned short* __restrict__ vT,
    unsigned short* __restrict__ nump, float* __restrict__ denp)
{
  __shared__ __align__(16) char smem[163840];
  char* kbuf = smem;            // [2][32768]
  char* vbuf = smem + 65536;    // [2][32768]
  char* Pb   = smem + 131072;   // [2][16384]

  const int t = threadIdx.x;
  const int w = t >> 6, l = t & 63;
  const int l31 = l & 31, hi = l >> 5;
  const int rw = w & 7;          // role-local wave id
  const int ts = t & 511;        // role-local thread id
  const int bid = blockIdx.x;
  const int split = bid & (KSPLIT - 1);
  const int mb = bid >> 2;
  const int q0 = mb * BM;
  const int kbase0 = split * (NROWS / KSPLIT);
  const char* kbc = (const char*)kb;
  const char* vtc = (const char*)vT;

  if (w < 8) {
    // ===================== PRODUCER: S-waves =====================
    const int sr = rw >> 1, sc = rw & 1;
    const int qrow = sr * 32 + l31;
    const int qrowg = q0 + qrow;         // global q row (for diag zeroing)
    const int krl = sc * 32 + l31;
    const int pswz = (qrow & 7) << 4;

    bf16x8 qa[16];
    {
      const unsigned short* qrowp = qb + (size_t)(q0 + qrow) * DDIM + hi * 8;
      #pragma unroll
      for (int m = 0; m < 16; m++) qa[m] = *(const bf16x8*)(qrowp + m * 16);
    }
    float denl = 0.f;

    auto stageK = [&](int buf, int it) {
      const char* ksrc = kbc + (size_t)(kbase0 + it * BK) * 512;
      #pragma unroll
      for (int i = 0; i < 4; i++) {
        int n = i * 512 + ts;
        int row = n >> 5, slot = n & 31;
        // rotation swizzle: lds[row][slot] = K[row][(slot-row)&31]
        gload_lds16(ksrc + row * 512 + (((slot - row) & 31) << 4),
                    kbuf + buf * 32768 + i * 8192 + rw * 1024);
      }
    };

    stageK(0, 0);
    asm volatile("s_waitcnt vmcnt(0)" ::: "memory");
    __builtin_amdgcn_sched_barrier(0);
    __builtin_amdgcn_s_barrier();           // prologue barrier
    __builtin_amdgcn_sched_barrier(0);

    for (int it = 0; it < NT; ++it) {
      const int cur = it & 1;
      if (it + 1 < NT) stageK(cur ^ 1, it + 1);
      __builtin_amdgcn_sched_barrier(0);

      const char* kcur = kbuf + cur * 32768;
      f32x16 sacc = (f32x16){0.f};
      #pragma unroll
      for (int m = 0; m < 16; m++) {
        bf16x8 kf = *(const bf16x8*)(kcur + krl * 512 +
                                     (((m * 2 + hi + krl) & 31) << 4));
        sacc = __builtin_amdgcn_mfma_f32_32x32x16_bf16(kf, qa[m], sacc, 0, 0, 0);
      }
      char* prowP = Pb + cur * 16384 + qrow * 128;
      // kcol_local for sacc[4q+jj] = 8q + 4hi + jj (C layout row index)
      const int dref = qrowg - (kbase0 + it * BK + sc * 32 + hi * 4);
      #pragma unroll
      for (int q = 0; q < 4; q++) {
        float v0 = fmaxf(sacc[4 * q + 0], 0.f);
        float v1 = fmaxf(sacc[4 * q + 1], 0.f);
        float v2 = fmaxf(sacc[4 * q + 2], 0.f);
        float v3 = fmaxf(sacc[4 * q + 3], 0.f);
        const int d = dref - 8 * q;     // zero diagonal element (w[i][i] = 0)
        if (d == 0) v0 = 0.f;
        else if (d == 1) v1 = 0.f;
        else if (d == 2) v2 = 0.f;
        else if (d == 3) v3 = 0.f;
        denl += (v0 + v1) + (v2 + v3);
        uint2 d2;
        d2.x = pack2bf(v0, v1);
        d2.y = pack2bf(v2, v3);
        *(uint2*)(prowP + ((sc * 64 + q * 16 + hi * 8) ^ pswz)) = d2;
      }
      asm volatile("s_waitcnt vmcnt(0) lgkmcnt(0)" ::: "memory");
      __builtin_amdgcn_sched_barrier(0);
      __builtin_amdgcn_s_barrier();
      __builtin_amdgcn_sched_barrier(0);
    }

    // den: lanes l and l+32 hold the same qrow's two kcol interleaves
    float d = denl;
    d += __shfl_xor(d, 32);
    if (l < 32)
      denp[((size_t)split * 2 + sc) * NROWS + q0 + sr * 32 + l] = d;
  } else {
    // ===================== CONSUMER: PV-waves =====================
    const int pr = rw >> 2, pc = rw & 3;
    const int pr0 = pr * 64 + l31, pr1 = pr * 64 + 32 + l31;

    f32x16 oacc[2][2];
    #pragma unroll
    for (int rt = 0; rt < 2; rt++)
      #pragma unroll
      for (int dt = 0; dt < 2; dt++)
        oacc[rt][dt] = (f32x16){0.f};

    auto stageV = [&](int buf, int it) {
      const char* vsrc = vtc + (size_t)(kbase0 + it * BK) * 2;
      #pragma unroll
      for (int i = 0; i < 4; i++) {
        int n = i * 512 + ts;
        int dd = n >> 3, slot = n & 7;
        // XOR-8 swizzle: lds[d][slot] = vT[d][slot ^ (d&7)]
        gload_lds16(vsrc + (size_t)dd * (NROWS * 2) + ((slot ^ (dd & 7)) * 16),
                    vbuf + buf * 32768 + i * 8192 + rw * 1024);
      }
    };

    __builtin_amdgcn_s_barrier();           // prologue barrier (match producer)
    __builtin_amdgcn_sched_barrier(0);

    for (int it = 0; it < NT; ++it) {
      const int cur = it & 1;
      stageV(cur, it);
      __builtin_amdgcn_sched_barrier(0);

      if (it > 0) {
        const char* Pprev = Pb + (cur ^ 1) * 16384;
        const char* vprev = vbuf + (cur ^ 1) * 32768;
        #pragma unroll
        for (int ch = 0; ch < 4; ch++) {
          const int cb = ch * 32 + hi * 16;
          bf16x8 pa0 = *(const bf16x8*)(Pprev + pr0 * 128 + (cb ^ ((pr0 & 7) << 4)));
          bf16x8 pa1 = *(const bf16x8*)(Pprev + pr1 * 128 + (cb ^ ((pr1 & 7) << 4)));
          #pragma unroll
          for (int dt = 0; dt < 2; dt++) {
            int dl = pc * 64 + dt * 32 + l31;
            bf16x8 vf = *(const bf16x8*)(vprev + dl * 128 + (cb ^ ((dl & 7) << 4)));
            oacc[0][dt] = __builtin_amdgcn_mfma_f32_32x32x16_bf16(pa0, vf, oacc[0][dt], 0, 0, 0);
            oacc[1][dt] = __builtin_amdgcn_mfma_f32_32x32x16_bf16(pa1, vf, oacc[1][dt], 0, 0, 0);
          }
        }
      }
      asm volatile("s_waitcnt vmcnt(0) lgkmcnt(0)" ::: "memory");
      __builtin_amdgcn_sched_barrier(0);
      __builtin_amdgcn_s_barrier();
      __builtin_amdgcn_sched_barrier(0);
    }

    // epilogue: PV(NT-1)
    {
      const int last = (NT - 1) & 1;
      const char* Pprev = Pb + last * 16384;
      const char* vprev = vbuf + last * 32768;
      #pragma unroll
      for (int ch = 0; ch < 4; ch++) {
        const int cb = ch * 32 + hi * 16;
        bf16x8 pa0 = *(const bf16x8*)(Pprev + pr0 * 128 + (cb ^ ((pr0 & 7) << 4)));
        bf16x8 pa1 = *(const bf16x8*)(Pprev + pr1 * 128 + (cb ^ ((pr1 & 7) << 4)));
        #pragma unroll
        for (int dt = 0; dt < 2; dt++) {
          int dl = pc * 64 + dt * 32 + l31;
          bf16x8 vf = *(const bf16x8*)(vprev + dl * 128 + (cb ^ ((dl & 7) << 4)));
          oacc[0][dt] = __builtin_amdgcn_mfma_f32_32x32x16_bf16(pa0, vf, oacc[0][dt], 0, 0, 0);
          oacc[1][dt] = __builtin_amdgcn_mfma_f32_32x32x16_bf16(pa1, vf, oacc[1][dt], 0, 0, 0);
        }
      }
    }

    // write numerator partials (fp16). C layout: col=lane&31, row=(r&3)+8*(r>>2)+4*hi
    unsigned short* np = nump + (size_t)split * NROWS * DDIM;
    #pragma unroll
    for (int rt = 0; rt < 2; rt++)
      #pragma unroll
      for (int dt = 0; dt < 2; dt++)
        #pragma unroll
        for (int r = 0; r < 16; r++) {
          int rowg = q0 + pr * 64 + rt * 32 + (r & 3) + 8 * (r >> 2) + 4 * hi;
          int col  = pc * 64 + dt * 32 + l31;
          np[(size_t)rowg * DDIM + col] = f2h_bits(oacc[rt][dt][r]);
        }
  }
}

// ---------------- kernel 3: combine partials (pure streaming) ----------------
// Diagonal already zeroed in attn; out = (Σ nump)/max(Σ denp, eps) + x.
__global__ __launch_bounds__(256) void combine_kernel(
    const float* __restrict__ x,
    const unsigned short* __restrict__ nump, const float* __restrict__ denp,
    float* __restrict__ out)
{
  const int t = threadIdx.x;
  const int w = t >> 6, l = t & 63;
  const int i = blockIdx.x * 4 + w;

  float den = 0.f;
  #pragma unroll
  for (int sp = 0; sp < KSPLIT * 2; sp++)
    den += denp[(size_t)sp * NROWS + i];
  float inv = 1.f / fmaxf(den, 1e-12f);

  const int d0 = l * 4;
  float4 acc = {0.f, 0.f, 0.f, 0.f};
  #pragma unroll
  for (int sp = 0; sp < KSPLIT; sp++) {
    ushort4 u4 = *(const ushort4*)(nump + ((size_t)sp * NROWS + i) * DDIM + d0);
    acc.x += h2f(u4.x); acc.y += h2f(u4.y);
    acc.z += h2f(u4.z); acc.w += h2f(u4.w);
  }
  float4 xx = *(const float4*)(x + (size_t)i * DDIM + d0);
  float4 o;
  o.x = acc.x * inv + xx.x;
  o.y = acc.y * inv + xx.y;
  o.z = acc.z * inv + xx.z;
  o.w = acc.w * inv + xx.w;
  *(float4*)(out + (size_t)i * DDIM + d0) = o;
}

extern "C" void kernel_launch(void* const* d_in, const int* in_sizes, int n_in,
                              void* d_out, int out_size, void* d_ws, size_t ws_size,
                              hipStream_t stream)
{
  const float* x  = (const float*)d_in[0];
  const float* Wq = (const float*)d_in[1];
  const float* bq = (const float*)d_in[2];
  const float* Wk = (const float*)d_in[3];
  const float* bk = (const float*)d_in[4];
  const float* Wv = (const float*)d_in[5];
  const float* bv = (const float*)d_in[6];

  char* ws = (char*)d_ws;
  unsigned short* xp   = (unsigned short*)(ws + 0);          // 4 MB (fragment-packed x)
  unsigned short* Wp   = (unsigned short*)(ws + 4194304);    // 384 KB (fragment-packed W)
  unsigned short* qb   = (unsigned short*)(ws + 4587520);    // 4 MB
  unsigned short* kb   = (unsigned short*)(ws + 8781824);    // 4 MB
  unsigned short* vT   = (unsigned short*)(ws + 12976128);   // 4 MB
  unsigned short* nump = (unsigned short*)(ws + 17170432);   // 16 MB (4 splits, fp16)
  float* denp = (float*)(ws + 33947648);                     // 256 KB (8 slices)

  convert_kernel<<<1120, 256, 0, stream>>>(x, Wq, Wk, Wv, xp, Wp);
  qkv_kernel<<<384, 256, 0, stream>>>(bq, bk, bv, xp, Wp, qb, kb, vT);
  attn_kernel<<<(NROWS / BM) * KSPLIT, 1024, 0, stream>>>(qb, kb, vT, nump, denp);
  combine_kernel<<<NROWS / 4, 256, 0, stream>>>(x, nump, denp, (float*)d_out);
}

// Round 14
// 122.638 us; speedup vs baseline: 1.0581x; 1.0581x over previous
//
#include <hip/hip_runtime.h>

#define NROWS 8192
#define DDIM  256
#define KSPLIT 4
#define BM 128
#define BK 64
#define NT (NROWS / KSPLIT / BK)   // 32 tiles per split

typedef __bf16 bf16x8 __attribute__((ext_vector_type(8)));
typedef float  f32x4  __attribute__((ext_vector_type(4)));
typedef float  f32x16 __attribute__((ext_vector_type(16)));

typedef __attribute__((address_space(1))) unsigned int uint_gas;
typedef __attribute__((address_space(3))) unsigned int uint_las;

__device__ __forceinline__ void gload_lds16(const void* g, void* l) {
  __builtin_amdgcn_global_load_lds((const uint_gas*)g, (uint_las*)l, 16, 0, 0);
}

__device__ __forceinline__ unsigned int f2bf_bits(float f) {
  union { float f; unsigned int u; } v; v.f = f;
  unsigned int r = v.u + 0x7FFFu + ((v.u >> 16) & 1u);
  return r >> 16;
}
__device__ __forceinline__ float bf2f(unsigned int b) {
  union { unsigned int u; float f; } v; v.u = b << 16;
  return v.f;
}
__device__ __forceinline__ unsigned int pack2bf(float a, float b) {
  union { unsigned int u; __bf16 h[2]; } p;
  p.h[0] = (__bf16)a; p.h[1] = (__bf16)b;
  return p.u;
}
__device__ __forceinline__ unsigned short f2h_bits(float f) {
  union { _Float16 h; unsigned short u; } c; c.h = (_Float16)f;
  return c.u;
}
__device__ __forceinline__ float h2f(unsigned short u) {
  union { unsigned short u; _Float16 h; } c; c.u = u;
  return (float)c.h;
}

// ---------------- kernel 0: fp32 -> bf16, MFMA-fragment-order packing ----------------
#define NXFRAG (512 * 8 * 64)        // 262144
#define NWFRAG (3 * 16 * 8 * 64)     // 24576
__global__ __launch_bounds__(256) void convert_kernel(
    const float* __restrict__ x, const float* __restrict__ wq,
    const float* __restrict__ wk, const float* __restrict__ wv,
    unsigned short* __restrict__ xp, unsigned short* __restrict__ Wp)
{
  int tid = blockIdx.x * 256 + threadIdx.x;
  const float* src;
  unsigned short* dst;
  int row, col;
  if (tid < NXFRAG) {
    int l = tid & 63, ks = (tid >> 6) & 7, rt = tid >> 9;
    src = x; dst = xp + (size_t)tid * 8;
    row = rt * 16 + (l & 15); col = ks * 32 + (l >> 4) * 8;
  } else {
    int fid = tid - NXFRAG;
    if (fid >= NWFRAG) return;
    int l = fid & 63, ks = (fid >> 6) & 7, ct = (fid >> 9) & 15, out = fid >> 13;
    src = (out == 0) ? wq : (out == 1) ? wk : wv;
    dst = Wp + (size_t)fid * 8;
    row = ct * 16 + (l & 15); col = ks * 32 + (l >> 4) * 8;
  }
  const float* p = src + (size_t)row * DDIM + col;
  float4 f0 = *(const float4*)p;
  float4 f1 = *(const float4*)(p + 4);
  ushort4 o0, o1;
  o0.x = (unsigned short)f2bf_bits(f0.x); o0.y = (unsigned short)f2bf_bits(f0.y);
  o0.z = (unsigned short)f2bf_bits(f0.z); o0.w = (unsigned short)f2bf_bits(f0.w);
  o1.x = (unsigned short)f2bf_bits(f1.x); o1.y = (unsigned short)f2bf_bits(f1.y);
  o1.z = (unsigned short)f2bf_bits(f1.z); o1.w = (unsigned short)f2bf_bits(f1.w);
  *(ushort4*)dst = o0;
  *(ushort4*)(dst + 4) = o1;
}

// ---------------- kernel 1: QKV projections + L2 norm + vT ----------------
__global__ __launch_bounds__(256) void qkv_kernel(
    const float* __restrict__ bq, const float* __restrict__ bk, const float* __restrict__ bv,
    const unsigned short* __restrict__ xp, const unsigned short* __restrict__ Wp,
    unsigned short* __restrict__ qb, unsigned short* __restrict__ kb,
    unsigned short* __restrict__ vT)
{
  __shared__ unsigned short vstage[DDIM * 72];
  const int t = threadIdx.x;
  const int w = t >> 6, l = t & 63;
  const int c = l & 15, g = l >> 4;
  const int out = blockIdx.x / 128;
  const int mb  = blockIdx.x % 128;
  const int row0 = mb * 64;
  const int rw = row0 + w * 16;
  const int rt = mb * 4 + w;           // global 16-row tile id

  bf16x8 a[8];
  #pragma unroll
  for (int ks = 0; ks < 8; ks++)
    a[ks] = *(const bf16x8*)(xp + ((size_t)(rt * 8 + ks) * 64 + l) * 8);

  const float* bias = (out == 0) ? bq : (out == 1) ? bk : bv;
  f32x4 vals[16];
  #pragma unroll
  for (int ct = 0; ct < 16; ct++) {
    f32x4 acc = {0.f, 0.f, 0.f, 0.f};
    #pragma unroll
    for (int ks = 0; ks < 8; ks++) {
      bf16x8 b = *(const bf16x8*)(Wp + ((size_t)((out * 16 + ct) * 8 + ks) * 64 + l) * 8);
      acc = __builtin_amdgcn_mfma_f32_16x16x32_bf16(a[ks], b, acc, 0, 0, 0);
    }
    float bias_v = bias[ct * 16 + c];
    #pragma unroll
    for (int r = 0; r < 4; r++) acc[r] += bias_v;
    vals[ct] = acc;
  }
  if (out < 2) {   // L2 normalize rows (q, k)
    #pragma unroll
    for (int r = 0; r < 4; r++) {
      float ss = 0.f;
      #pragma unroll
      for (int ct = 0; ct < 16; ct++) ss += vals[ct][r] * vals[ct][r];
      ss += __shfl_xor(ss, 1); ss += __shfl_xor(ss, 2);
      ss += __shfl_xor(ss, 4); ss += __shfl_xor(ss, 8);
      float inv = 1.f / fmaxf(sqrtf(ss), 1e-12f);
      #pragma unroll
      for (int ct = 0; ct < 16; ct++) vals[ct][r] *= inv;
    }
    unsigned short* dst = (out == 0) ? qb : kb;
    #pragma unroll
    for (int ct = 0; ct < 16; ct++) {
      #pragma unroll
      for (int r = 0; r < 4; r++) {
        unsigned int bits = f2bf_bits(vals[ct][r]);
        unsigned int ob = (unsigned int)__shfl_xor((int)bits, 1);
        if (!(l & 1))
          *(unsigned int*)(dst + (size_t)(rw + g * 4 + r) * DDIM + ct * 16 + c) =
              bits | (ob << 16);
      }
    }
  } else {
    #pragma unroll
    for (int ct = 0; ct < 16; ct++)
      #pragma unroll
      for (int r = 0; r < 4; r++)
        vstage[(ct * 16 + c) * 72 + (w * 16 + g * 4 + r)] =
            (unsigned short)f2bf_bits(vals[ct][r]);
    __syncthreads();
    #pragma unroll
    for (int p = 0; p < 8; p++) {
      int dd = (t >> 3) + p * 32;
      int ch = t & 7;
      *(uint4*)(vT + (size_t)dd * NROWS + row0 + ch * 8) =
          *(const uint4*)(vstage + dd * 72 + ch * 8);
    }
  }
}

// ---------------- kernel 2: fused relu-attention, producer-consumer waves ----------------
// 1024 threads = 16 waves @ 4/SIMD. Waves 0-7 (S): hold qa, compute S^T=K.Q^T,
// pack P->Pb[cur] (diag zeroed ONLY under a block-uniform overlap guard — R13's
// unconditional per-lane branch chain cost +17 µs), stage K, track den.
// Waves 8-15 (PV): compute P(it-1).V(it-1), stage V, write nump.
__global__ __launch_bounds__(1024, 4) void attn_kernel(
    const unsigned short* __restrict__ qb, const unsigned short* __restrict__ kb,
    const unsigned short* __restrict__ vT,
    unsigned short* __restrict__ nump, float* __restrict__ denp)
{
  __shared__ __align__(16) char smem[163840];
  char* kbuf = smem;            // [2][32768]
  char* vbuf = smem + 65536;    // [2][32768]
  char* Pb   = smem + 131072;   // [2][16384]

  const int t = threadIdx.x;
  const int w = t >> 6, l = t & 63;
  const int l31 = l & 31, hi = l >> 5;
  const int rw = w & 7;          // role-local wave id
  const int ts = t & 511;        // role-local thread id
  const int bid = blockIdx.x;
  const int split = bid & (KSPLIT - 1);
  const int mb = bid >> 2;
  const int q0 = mb * BM;
  const int kbase0 = split * (NROWS / KSPLIT);
  const char* kbc = (const char*)kb;
  const char* vtc = (const char*)vT;

  if (w < 8) {
    // ===================== PRODUCER: S-waves =====================
    const int sr = rw >> 1, sc = rw & 1;
    const int qrow = sr * 32 + l31;
    const int qrowg = q0 + qrow;         // global q row (for diag zeroing)
    const int krl = sc * 32 + l31;
    const int pswz = (qrow & 7) << 4;

    bf16x8 qa[16];
    {
      const unsigned short* qrowp = qb + (size_t)(q0 + qrow) * DDIM + hi * 8;
      #pragma unroll
      for (int m = 0; m < 16; m++) qa[m] = *(const bf16x8*)(qrowp + m * 16);
    }
    float denl = 0.f;

    auto stageK = [&](int buf, int it) {
      const char* ksrc = kbc + (size_t)(kbase0 + it * BK) * 512;
      #pragma unroll
      for (int i = 0; i < 4; i++) {
        int n = i * 512 + ts;
        int row = n >> 5, slot = n & 31;
        // rotation swizzle: lds[row][slot] = K[row][(slot-row)&31]
        gload_lds16(ksrc + row * 512 + (((slot - row) & 31) << 4),
                    kbuf + buf * 32768 + i * 8192 + rw * 1024);
      }
    };

    stageK(0, 0);
    asm volatile("s_waitcnt vmcnt(0)" ::: "memory");
    __builtin_amdgcn_sched_barrier(0);
    __builtin_amdgcn_s_barrier();           // prologue barrier
    __builtin_amdgcn_sched_barrier(0);

    for (int it = 0; it < NT; ++it) {
      const int cur = it & 1;
      if (it + 1 < NT) stageK(cur ^ 1, it + 1);
      __builtin_amdgcn_sched_barrier(0);

      const char* kcur = kbuf + cur * 32768;
      f32x16 sacc = (f32x16){0.f};
      #pragma unroll
      for (int m = 0; m < 16; m++) {
        bf16x8 kf = *(const bf16x8*)(kcur + krl * 512 +
                                     (((m * 2 + hi + krl) & 31) << 4));
        sacc = __builtin_amdgcn_mfma_f32_32x32x16_bf16(kf, qa[m], sacc, 0, 0, 0);
      }
      char* prowP = Pb + cur * 16384 + qrow * 128;
      const int kbase = kbase0 + it * BK;
      // block-uniform: can this tile touch the diagonal at all?
      if (__builtin_expect(kbase < q0 + BM && q0 < kbase + BK, 0)) {
        // cold path (~2% of tiles): per-lane diag zeroing via ternaries
        const int dref = qrowg - (kbase + sc * 32 + hi * 4);
        #pragma unroll
        for (int q = 0; q < 4; q++) {
          float v0 = fmaxf(sacc[4 * q + 0], 0.f);
          float v1 = fmaxf(sacc[4 * q + 1], 0.f);
          float v2 = fmaxf(sacc[4 * q + 2], 0.f);
          float v3 = fmaxf(sacc[4 * q + 3], 0.f);
          const int d = dref - 8 * q;
          v0 = (d == 0) ? 0.f : v0;
          v1 = (d == 1) ? 0.f : v1;
          v2 = (d == 2) ? 0.f : v2;
          v3 = (d == 3) ? 0.f : v3;
          denl += (v0 + v1) + (v2 + v3);
          uint2 d2;
          d2.x = pack2bf(v0, v1);
          d2.y = pack2bf(v2, v3);
          *(uint2*)(prowP + ((sc * 64 + q * 16 + hi * 8) ^ pswz)) = d2;
        }
      } else {
        // hot path: branch-free pack (R11 code verbatim)
        #pragma unroll
        for (int q = 0; q < 4; q++) {
          float v0 = fmaxf(sacc[4 * q + 0], 0.f);
          float v1 = fmaxf(sacc[4 * q + 1], 0.f);
          float v2 = fmaxf(sacc[4 * q + 2], 0.f);
          float v3 = fmaxf(sacc[4 * q + 3], 0.f);
          denl += (v0 + v1) + (v2 + v3);
          uint2 d2;
          d2.x = pack2bf(v0, v1);
          d2.y = pack2bf(v2, v3);
          *(uint2*)(prowP + ((sc * 64 + q * 16 + hi * 8) ^ pswz)) = d2;
        }
      }
      asm volatile("s_waitcnt vmcnt(0) lgkmcnt(0)" ::: "memory");
      __builtin_amdgcn_sched_barrier(0);
      __builtin_amdgcn_s_barrier();
      __builtin_amdgcn_sched_barrier(0);
    }

    // den: lanes l and l+32 hold the same qrow's two kcol interleaves
    float d = denl;
    d += __shfl_xor(d, 32);
    if (l < 32)
      denp[((size_t)split * 2 + sc) * NROWS + q0 + sr * 32 + l] = d;
  } else {
    // ===================== CONSUMER: PV-waves =====================
    const int pr = rw >> 2, pc = rw & 3;
    const int pr0 = pr * 64 + l31, pr1 = pr * 64 + 32 + l31;

    f32x16 oacc[2][2];
    #pragma unroll
    for (int rt = 0; rt < 2; rt++)
      #pragma unroll
      for (int dt = 0; dt < 2; dt++)
        oacc[rt][dt] = (f32x16){0.f};

    auto stageV = [&](int buf, int it) {
      const char* vsrc = vtc + (size_t)(kbase0 + it * BK) * 2;
      #pragma unroll
      for (int i = 0; i < 4; i++) {
        int n = i * 512 + ts;
        int dd = n >> 3, slot = n & 7;
        // XOR-8 swizzle: lds[d][slot] = vT[d][slot ^ (d&7)]
        gload_lds16(vsrc + (size_t)dd * (NROWS * 2) + ((slot ^ (dd & 7)) * 16),
                    vbuf + buf * 32768 + i * 8192 + rw * 1024);
      }
    };

    __builtin_amdgcn_s_barrier();           // prologue barrier (match producer)
    __builtin_amdgcn_sched_barrier(0);

    for (int it = 0; it < NT; ++it) {
      const int cur = it & 1;
      stageV(cur, it);
      __builtin_amdgcn_sched_barrier(0);

      if (it > 0) {
        const char* Pprev = Pb + (cur ^ 1) * 16384;
        const char* vprev = vbuf + (cur ^ 1) * 32768;
        #pragma unroll
        for (int ch = 0; ch < 4; ch++) {
          const int cb = ch * 32 + hi * 16;
          bf16x8 pa0 = *(const bf16x8*)(Pprev + pr0 * 128 + (cb ^ ((pr0 & 7) << 4)));
          bf16x8 pa1 = *(const bf16x8*)(Pprev + pr1 * 128 + (cb ^ ((pr1 & 7) << 4)));
          #pragma unroll
          for (int dt = 0; dt < 2; dt++) {
            int dl = pc * 64 + dt * 32 + l31;
            bf16x8 vf = *(const bf16x8*)(vprev + dl * 128 + (cb ^ ((dl & 7) << 4)));
            oacc[0][dt] = __builtin_amdgcn_mfma_f32_32x32x16_bf16(pa0, vf, oacc[0][dt], 0, 0, 0);
            oacc[1][dt] = __builtin_amdgcn_mfma_f32_32x32x16_bf16(pa1, vf, oacc[1][dt], 0, 0, 0);
          }
        }
      }
      asm volatile("s_waitcnt vmcnt(0) lgkmcnt(0)" ::: "memory");
      __builtin_amdgcn_sched_barrier(0);
      __builtin_amdgcn_s_barrier();
      __builtin_amdgcn_sched_barrier(0);
    }

    // epilogue: PV(NT-1)
    {
      const int last = (NT - 1) & 1;
      const char* Pprev = Pb + last * 16384;
      const char* vprev = vbuf + last * 32768;
      #pragma unroll
      for (int ch = 0; ch < 4; ch++) {
        const int cb = ch * 32 + hi * 16;
        bf16x8 pa0 = *(const bf16x8*)(Pprev + pr0 * 128 + (cb ^ ((pr0 & 7) << 4)));
        bf16x8 pa1 = *(const bf16x8*)(Pprev + pr1 * 128 + (cb ^ ((pr1 & 7) << 4)));
        #pragma unroll
        for (int dt = 0; dt < 2; dt++) {
          int dl = pc * 64 + dt * 32 + l31;
          bf16x8 vf = *(const bf16x8*)(vprev + dl * 128 + (cb ^ ((dl & 7) << 4)));
          oacc[0][dt] = __builtin_amdgcn_mfma_f32_32x32x16_bf16(pa0, vf, oacc[0][dt], 0, 0, 0);
          oacc[1][dt] = __builtin_amdgcn_mfma_f32_32x32x16_bf16(pa1, vf, oacc[1][dt], 0, 0, 0);
        }
      }
    }

    // write numerator partials (fp16). C layout: col=lane&31, row=(r&3)+8*(r>>2)+4*hi
    unsigned short* np = nump + (size_t)split * NROWS * DDIM;
    #pragma unroll
    for (int rt = 0; rt < 2; rt++)
      #pragma unroll
      for (int dt = 0; dt < 2; dt++)
        #pragma unroll
        for (int r = 0; r < 16; r++) {
          int rowg = q0 + pr * 64 + rt * 32 + (r & 3) + 8 * (r >> 2) + 4 * hi;
          int col  = pc * 64 + dt * 32 + l31;
          np[(size_t)rowg * DDIM + col] = f2h_bits(oacc[rt][dt][r]);
        }
  }
}

// ---------------- kernel 3: combine partials (pure streaming) ----------------
__global__ __launch_bounds__(256) void combine_kernel(
    const float* __restrict__ x,
    const unsigned short* __restrict__ nump, const float* __restrict__ denp,
    float* __restrict__ out)
{
  const int t = threadIdx.x;
  const int w = t >> 6, l = t & 63;
  const int i = blockIdx.x * 4 + w;

  float den = 0.f;
  #pragma unroll
  for (int sp = 0; sp < KSPLIT * 2; sp++)
    den += denp[(size_t)sp * NROWS + i];
  float inv = 1.f / fmaxf(den, 1e-12f);

  const int d0 = l * 4;
  float4 acc = {0.f, 0.f, 0.f, 0.f};
  #pragma unroll
  for (int sp = 0; sp < KSPLIT; sp++) {
    ushort4 u4 = *(const ushort4*)(nump + ((size_t)sp * NROWS + i) * DDIM + d0);
    acc.x += h2f(u4.x); acc.y += h2f(u4.y);
    acc.z += h2f(u4.z); acc.w += h2f(u4.w);
  }
  float4 xx = *(const float4*)(x + (size_t)i * DDIM + d0);
  float4 o;
  o.x = acc.x * inv + xx.x;
  o.y = acc.y * inv + xx.y;
  o.z = acc.z * inv + xx.z;
  o.w = acc.w * inv + xx.w;
  *(float4*)(out + (size_t)i * DDIM + d0) = o;
}

extern "C" void kernel_launch(void* const* d_in, const int* in_sizes, int n_in,
                              void* d_out, int out_size, void* d_ws, size_t ws_size,
                              hipStream_t stream)
{
  const float* x  = (const float*)d_in[0];
  const float* Wq = (const float*)d_in[1];
  const float* bq = (const float*)d_in[2];
  const float* Wk = (const float*)d_in[3];
  const float* bk = (const float*)d_in[4];
  const float* Wv = (const float*)d_in[5];
  const float* bv = (const float*)d_in[6];

  char* ws = (char*)d_ws;
  unsigned short* xp   = (unsigned short*)(ws + 0);          // 4 MB (fragment-packed x)
  unsigned short* Wp   = (unsigned short*)(ws + 4194304);    // 384 KB (fragment-packed W)
  unsigned short* qb   = (unsigned short*)(ws + 4587520);    // 4 MB
  unsigned short* kb   = (unsigned short*)(ws + 8781824);    // 4 MB
  unsigned short* vT   = (unsigned short*)(ws + 12976128);   // 4 MB
  unsigned short* nump = (unsigned short*)(ws + 17170432);   // 16 MB (4 splits, fp16)
  float* denp = (float*)(ws + 33947648);                     // 256 KB (8 slices)

  convert_kernel<<<1120, 256, 0, stream>>>(x, Wq, Wk, Wv, xp, Wp);
  qkv_kernel<<<384, 256, 0, stream>>>(bq, bk, bv, xp, Wp, qb, kb, vT);
  attn_kernel<<<(NROWS / BM) * KSPLIT, 1024, 0, stream>>>(qb, kb, vT, nump, denp);
  combine_kernel<<<NROWS / 4, 256, 0, stream>>>(x, nump, denp, (float*)d_out);
}

// Round 15
// 122.041 us; speedup vs baseline: 1.0633x; 1.0049x over previous
//
#include <hip/hip_runtime.h>

#define NROWS 8192
#define DDIM  256
#define KSPLIT 4
#define BM 128
#define BK 64
#define NT (NROWS / KSPLIT / BK)   // 32 tiles per split

typedef __bf16 bf16x8 __attribute__((ext_vector_type(8)));
typedef float  f32x4  __attribute__((ext_vector_type(4)));
typedef float  f32x16 __attribute__((ext_vector_type(16)));

typedef __attribute__((address_space(1))) unsigned int uint_gas;
typedef __attribute__((address_space(3))) unsigned int uint_las;

__device__ __forceinline__ void gload_lds16(const void* g, void* l) {
  __builtin_amdgcn_global_load_lds((const uint_gas*)g, (uint_las*)l, 16, 0, 0);
}

__device__ __forceinline__ unsigned int f2bf_bits(float f) {
  union { float f; unsigned int u; } v; v.f = f;
  unsigned int r = v.u + 0x7FFFu + ((v.u >> 16) & 1u);
  return r >> 16;
}
__device__ __forceinline__ float bf2f(unsigned int b) {
  union { unsigned int u; float f; } v; v.u = b << 16;
  return v.f;
}
__device__ __forceinline__ unsigned int pack2bf(float a, float b) {
  union { unsigned int u; __bf16 h[2]; } p;
  p.h[0] = (__bf16)a; p.h[1] = (__bf16)b;
  return p.u;
}
__device__ __forceinline__ unsigned short f2h_bits(float f) {
  union { _Float16 h; unsigned short u; } c; c.h = (_Float16)f;
  return c.u;
}
__device__ __forceinline__ float h2f(unsigned short u) {
  union { unsigned short u; _Float16 h; } c; c.u = u;
  return (float)c.h;
}

// ---------------- kernel 0: fp32 -> bf16, MFMA-fragment-order packing ----------------
#define NXFRAG (512 * 8 * 64)        // 262144
#define NWFRAG (3 * 16 * 8 * 64)     // 24576
__global__ __launch_bounds__(256) void convert_kernel(
    const float* __restrict__ x, const float* __restrict__ wq,
    const float* __restrict__ wk, const float* __restrict__ wv,
    unsigned short* __restrict__ xp, unsigned short* __restrict__ Wp)
{
  int tid = blockIdx.x * 256 + threadIdx.x;
  const float* src;
  unsigned short* dst;
  int row, col;
  if (tid < NXFRAG) {
    int l = tid & 63, ks = (tid >> 6) & 7, rt = tid >> 9;
    src = x; dst = xp + (size_t)tid * 8;
    row = rt * 16 + (l & 15); col = ks * 32 + (l >> 4) * 8;
  } else {
    int fid = tid - NXFRAG;
    if (fid >= NWFRAG) return;
    int l = fid & 63, ks = (fid >> 6) & 7, ct = (fid >> 9) & 15, out = fid >> 13;
    src = (out == 0) ? wq : (out == 1) ? wk : wv;
    dst = Wp + (size_t)fid * 8;
    row = ct * 16 + (l & 15); col = ks * 32 + (l >> 4) * 8;
  }
  const float* p = src + (size_t)row * DDIM + col;
  float4 f0 = *(const float4*)p;
  float4 f1 = *(const float4*)(p + 4);
  ushort4 o0, o1;
  o0.x = (unsigned short)f2bf_bits(f0.x); o0.y = (unsigned short)f2bf_bits(f0.y);
  o0.z = (unsigned short)f2bf_bits(f0.z); o0.w = (unsigned short)f2bf_bits(f0.w);
  o1.x = (unsigned short)f2bf_bits(f1.x); o1.y = (unsigned short)f2bf_bits(f1.y);
  o1.z = (unsigned short)f2bf_bits(f1.z); o1.w = (unsigned short)f2bf_bits(f1.w);
  *(ushort4*)dst = o0;
  *(ushort4*)(dst + 4) = o1;
}

// ---------------- kernel 1: QKV projections + L2 norm + vtp (staged-order V) ----------------
// vtp layout = exact LDS image per 64-k window: [window 128][blk=d/32 (8)][s=k16B (8)][d&31][16B]
// element (w,blk,s,d31)[j] = v[w*64 + s*8 + j][blk*32 + d31]
__global__ __launch_bounds__(256) void qkv_kernel(
    const float* __restrict__ bq, const float* __restrict__ bk, const float* __restrict__ bv,
    const unsigned short* __restrict__ xp, const unsigned short* __restrict__ Wp,
    unsigned short* __restrict__ qb, unsigned short* __restrict__ kb,
    unsigned short* __restrict__ vtp)
{
  __shared__ unsigned short vstage[DDIM * 72];
  const int t = threadIdx.x;
  const int w = t >> 6, l = t & 63;
  const int c = l & 15, g = l >> 4;
  const int out = blockIdx.x / 128;
  const int mb  = blockIdx.x % 128;
  const int row0 = mb * 64;
  const int rw = row0 + w * 16;
  const int rt = mb * 4 + w;           // global 16-row tile id

  bf16x8 a[8];
  #pragma unroll
  for (int ks = 0; ks < 8; ks++)
    a[ks] = *(const bf16x8*)(xp + ((size_t)(rt * 8 + ks) * 64 + l) * 8);

  const float* bias = (out == 0) ? bq : (out == 1) ? bk : bv;
  f32x4 vals[16];
  #pragma unroll
  for (int ct = 0; ct < 16; ct++) {
    f32x4 acc = {0.f, 0.f, 0.f, 0.f};
    #pragma unroll
    for (int ks = 0; ks < 8; ks++) {
      bf16x8 b = *(const bf16x8*)(Wp + ((size_t)((out * 16 + ct) * 8 + ks) * 64 + l) * 8);
      acc = __builtin_amdgcn_mfma_f32_16x16x32_bf16(a[ks], b, acc, 0, 0, 0);
    }
    float bias_v = bias[ct * 16 + c];
    #pragma unroll
    for (int r = 0; r < 4; r++) acc[r] += bias_v;
    vals[ct] = acc;
  }
  if (out < 2) {   // L2 normalize rows (q, k)
    #pragma unroll
    for (int r = 0; r < 4; r++) {
      float ss = 0.f;
      #pragma unroll
      for (int ct = 0; ct < 16; ct++) ss += vals[ct][r] * vals[ct][r];
      ss += __shfl_xor(ss, 1); ss += __shfl_xor(ss, 2);
      ss += __shfl_xor(ss, 4); ss += __shfl_xor(ss, 8);
      float inv = 1.f / fmaxf(sqrtf(ss), 1e-12f);
      #pragma unroll
      for (int ct = 0; ct < 16; ct++) vals[ct][r] *= inv;
    }
    unsigned short* dst = (out == 0) ? qb : kb;
    #pragma unroll
    for (int ct = 0; ct < 16; ct++) {
      #pragma unroll
      for (int r = 0; r < 4; r++) {
        unsigned int bits = f2bf_bits(vals[ct][r]);
        unsigned int ob = (unsigned int)__shfl_xor((int)bits, 1);
        if (!(l & 1))
          *(unsigned int*)(dst + (size_t)(rw + g * 4 + r) * DDIM + ct * 16 + c) =
              bits | (ob << 16);
      }
    }
  } else {
    #pragma unroll
    for (int ct = 0; ct < 16; ct++)
      #pragma unroll
      for (int r = 0; r < 4; r++)
        vstage[(ct * 16 + c) * 72 + (w * 16 + g * 4 + r)] =
            (unsigned short)f2bf_bits(vals[ct][r]);
    __syncthreads();
    // write staged-order image: chunk n -> (blk = n>>8, s = (n>>5)&7, d31 = n&31)
    unsigned short* wdst = vtp + (size_t)mb * 16384;
    #pragma unroll
    for (int p = 0; p < 8; p++) {
      int n = p * 256 + t;
      int dg = ((n >> 8) << 5) + (n & 31);   // d row 0..255
      int s  = (n >> 5) & 7;
      *(uint4*)(wdst + (size_t)n * 8) = *(const uint4*)(vstage + dg * 72 + s * 8);
    }
  }
}

// ---------------- kernel 2: fused relu-attention, producer-consumer waves ----------------
// 1024 threads = 16 waves @ 4/SIMD. Waves 0-7 (S): hold qa, compute S^T=K.Q^T,
// pack P->Pb[cur] in slot-major layout, stage K, track den (diag zeroed under
// block-uniform guard). Waves 8-15 (PV): compute P(it-1).V(it-1), stage V
// (linear copy of pre-packed vtp), write nump.
// Slot-major layouts: P: [blk=row/32 (4)][s (8)][row&31][16B]; vbuf: same with d rows.
// All pa/vf reads: fixed slot, 32 consecutive rows -> 512B contiguous (conflict-free).
__global__ __launch_bounds__(1024, 4) void attn_kernel(
    const unsigned short* __restrict__ qb, const unsigned short* __restrict__ kb,
    const unsigned short* __restrict__ vtp,
    unsigned short* __restrict__ nump, float* __restrict__ denp)
{
  __shared__ __align__(16) char smem[163840];
  char* kbuf = smem;            // [2][32768]
  char* vbuf = smem + 65536;    // [2][32768]
  char* Pb   = smem + 131072;   // [2][16384]

  const int t = threadIdx.x;
  const int w = t >> 6, l = t & 63;
  const int l31 = l & 31, hi = l >> 5;
  const int rw = w & 7;          // role-local wave id
  const int ts = t & 511;        // role-local thread id
  const int bid = blockIdx.x;
  const int split = bid & (KSPLIT - 1);
  const int mb = bid >> 2;
  const int q0 = mb * BM;
  const int kbase0 = split * (NROWS / KSPLIT);
  const char* kbc = (const char*)kb;
  const char* vtc = (const char*)vtp;

  if (w < 8) {
    // ===================== PRODUCER: S-waves =====================
    const int sr = rw >> 1, sc = rw & 1;
    const int qrow = sr * 32 + l31;
    const int qrowg = q0 + qrow;
    const int krl = sc * 32 + l31;

    bf16x8 qa[16];
    {
      const unsigned short* qrowp = qb + (size_t)(q0 + qrow) * DDIM + hi * 8;
      #pragma unroll
      for (int m = 0; m < 16; m++) qa[m] = *(const bf16x8*)(qrowp + m * 16);
    }
    float denl = 0.f;

    auto stageK = [&](int buf, int it) {
      const char* ksrc = kbc + (size_t)(kbase0 + it * BK) * 512;
      #pragma unroll
      for (int i = 0; i < 4; i++) {
        int n = i * 512 + ts;
        int row = n >> 5, slot = n & 31;
        // rotation swizzle: lds[row][slot] = K[row][(slot-row)&31]
        gload_lds16(ksrc + row * 512 + (((slot - row) & 31) << 4),
                    kbuf + buf * 32768 + i * 8192 + rw * 1024);
      }
    };

    stageK(0, 0);
    asm volatile("s_waitcnt vmcnt(0)" ::: "memory");
    __builtin_amdgcn_sched_barrier(0);
    __builtin_amdgcn_s_barrier();           // prologue barrier
    __builtin_amdgcn_sched_barrier(0);

    for (int it = 0; it < NT; ++it) {
      const int cur = it & 1;
      if (it + 1 < NT) stageK(cur ^ 1, it + 1);
      __builtin_amdgcn_sched_barrier(0);

      const char* kcur = kbuf + cur * 32768;
      f32x16 sacc = (f32x16){0.f};
      #pragma unroll
      for (int m = 0; m < 16; m++) {
        bf16x8 kf = *(const bf16x8*)(kcur + krl * 512 +
                                     (((m * 2 + hi + krl) & 31) << 4));
        sacc = __builtin_amdgcn_mfma_f32_32x32x16_bf16(kf, qa[m], sacc, 0, 0, 0);
      }
      // P pack: slot-major — byte = sr*4096 + (sc*4+q)*512 + l31*16 + hi*8
      char* pbase = Pb + cur * 16384 + sr * 4096 + l31 * 16 + hi * 8;
      const int kbase = kbase0 + it * BK;
      if (__builtin_expect(kbase < q0 + BM && q0 < kbase + BK, 0)) {
        // cold path (~2% of tiles): per-lane diag zeroing via ternaries
        const int dref = qrowg - (kbase + sc * 32 + hi * 4);
        #pragma unroll
        for (int q = 0; q < 4; q++) {
          float v0 = fmaxf(sacc[4 * q + 0], 0.f);
          float v1 = fmaxf(sacc[4 * q + 1], 0.f);
          float v2 = fmaxf(sacc[4 * q + 2], 0.f);
          float v3 = fmaxf(sacc[4 * q + 3], 0.f);
          const int d = dref - 8 * q;
          v0 = (d == 0) ? 0.f : v0;
          v1 = (d == 1) ? 0.f : v1;
          v2 = (d == 2) ? 0.f : v2;
          v3 = (d == 3) ? 0.f : v3;
          denl += (v0 + v1) + (v2 + v3);
          uint2 d2;
          d2.x = pack2bf(v0, v1);
          d2.y = pack2bf(v2, v3);
          *(uint2*)(pbase + (sc * 4 + q) * 512) = d2;
        }
      } else {
        // hot path: branch-free pack
        #pragma unroll
        for (int q = 0; q < 4; q++) {
          float v0 = fmaxf(sacc[4 * q + 0], 0.f);
          float v1 = fmaxf(sacc[4 * q + 1], 0.f);
          float v2 = fmaxf(sacc[4 * q + 2], 0.f);
          float v3 = fmaxf(sacc[4 * q + 3], 0.f);
          denl += (v0 + v1) + (v2 + v3);
          uint2 d2;
          d2.x = pack2bf(v0, v1);
          d2.y = pack2bf(v2, v3);
          *(uint2*)(pbase + (sc * 4 + q) * 512) = d2;
        }
      }
      asm volatile("s_waitcnt vmcnt(0) lgkmcnt(0)" ::: "memory");
      __builtin_amdgcn_sched_barrier(0);
      __builtin_amdgcn_s_barrier();
      __builtin_amdgcn_sched_barrier(0);
    }

    // den: lanes l and l+32 hold the same qrow's two kcol interleaves
    float d = denl;
    d += __shfl_xor(d, 32);
    if (l < 32)
      denp[((size_t)split * 2 + sc) * NROWS + q0 + sr * 32 + l] = d;
  } else {
    // ===================== CONSUMER: PV-waves =====================
    const int pr = rw >> 2, pc = rw & 3;

    f32x16 oacc[2][2];
    #pragma unroll
    for (int rt = 0; rt < 2; rt++)
      #pragma unroll
      for (int dt = 0; dt < 2; dt++)
        oacc[rt][dt] = (f32x16){0.f};

    auto stageV = [&](int buf, int it) {
      // vtp is pre-packed in LDS image order: pure linear coalesced copy
      const char* vsrc = vtc + (size_t)((kbase0 + it * BK) >> 6) * 32768;
      #pragma unroll
      for (int i = 0; i < 4; i++) {
        int n = i * 512 + ts;
        gload_lds16(vsrc + n * 16,
                    vbuf + buf * 32768 + i * 8192 + rw * 1024);
      }
    };

    __builtin_amdgcn_s_barrier();           // prologue barrier (match producer)
    __builtin_amdgcn_sched_barrier(0);

    for (int it = 0; it < NT; ++it) {
      const int cur = it & 1;
      stageV(cur, it);
      __builtin_amdgcn_sched_barrier(0);

      if (it > 0) {
        const char* Pprev = Pb + (cur ^ 1) * 16384;
        const char* vprev = vbuf + (cur ^ 1) * 32768;
        #pragma unroll
        for (int ch = 0; ch < 4; ch++) {
          const int s512 = (ch * 2 + hi) * 512 + l31 * 16;
          bf16x8 pa0 = *(const bf16x8*)(Pprev + (pr * 2 + 0) * 4096 + s512);
          bf16x8 pa1 = *(const bf16x8*)(Pprev + (pr * 2 + 1) * 4096 + s512);
          #pragma unroll
          for (int dt = 0; dt < 2; dt++) {
            bf16x8 vf = *(const bf16x8*)(vprev + (pc * 2 + dt) * 4096 + s512);
            oacc[0][dt] = __builtin_amdgcn_mfma_f32_32x32x16_bf16(pa0, vf, oacc[0][dt], 0, 0, 0);
            oacc[1][dt] = __builtin_amdgcn_mfma_f32_32x32x16_bf16(pa1, vf, oacc[1][dt], 0, 0, 0);
          }
        }
      }
      asm volatile("s_waitcnt vmcnt(0) lgkmcnt(0)" ::: "memory");
      __builtin_amdgcn_sched_barrier(0);
      __builtin_amdgcn_s_barrier();
      __builtin_amdgcn_sched_barrier(0);
    }

    // epilogue: PV(NT-1)
    {
      const int last = (NT - 1) & 1;
      const char* Pprev = Pb + last * 16384;
      const char* vprev = vbuf + last * 32768;
      #pragma unroll
      for (int ch = 0; ch < 4; ch++) {
        const int s512 = (ch * 2 + hi) * 512 + l31 * 16;
        bf16x8 pa0 = *(const bf16x8*)(Pprev + (pr * 2 + 0) * 4096 + s512);
        bf16x8 pa1 = *(const bf16x8*)(Pprev + (pr * 2 + 1) * 4096 + s512);
        #pragma unroll
        for (int dt = 0; dt < 2; dt++) {
          bf16x8 vf = *(const bf16x8*)(vprev + (pc * 2 + dt) * 4096 + s512);
          oacc[0][dt] = __builtin_amdgcn_mfma_f32_32x32x16_bf16(pa0, vf, oacc[0][dt], 0, 0, 0);
          oacc[1][dt] = __builtin_amdgcn_mfma_f32_32x32x16_bf16(pa1, vf, oacc[1][dt], 0, 0, 0);
        }
      }
    }

    // write numerator partials (fp16). C layout: col=lane&31, row=(r&3)+8*(r>>2)+4*hi
    unsigned short* np = nump + (size_t)split * NROWS * DDIM;
    #pragma unroll
    for (int rt = 0; rt < 2; rt++)
      #pragma unroll
      for (int dt = 0; dt < 2; dt++)
        #pragma unroll
        for (int r = 0; r < 16; r++) {
          int rowg = q0 + pr * 64 + rt * 32 + (r & 3) + 8 * (r >> 2) + 4 * hi;
          int col  = pc * 64 + dt * 32 + l31;
          np[(size_t)rowg * DDIM + col] = f2h_bits(oacc[rt][dt][r]);
        }
  }
}

// ---------------- kernel 3: combine partials (pure streaming) ----------------
__global__ __launch_bounds__(256) void combine_kernel(
    const float* __restrict__ x,
    const unsigned short* __restrict__ nump, const float* __restrict__ denp,
    float* __restrict__ out)
{
  const int t = threadIdx.x;
  const int w = t >> 6, l = t & 63;
  const int i = blockIdx.x * 4 + w;

  float den = 0.f;
  #pragma unroll
  for (int sp = 0; sp < KSPLIT * 2; sp++)
    den += denp[(size_t)sp * NROWS + i];
  float inv = 1.f / fmaxf(den, 1e-12f);

  const int d0 = l * 4;
  float4 acc = {0.f, 0.f, 0.f, 0.f};
  #pragma unroll
  for (int sp = 0; sp < KSPLIT; sp++) {
    ushort4 u4 = *(const ushort4*)(nump + ((size_t)sp * NROWS + i) * DDIM + d0);
    acc.x += h2f(u4.x); acc.y += h2f(u4.y);
    acc.z += h2f(u4.z); acc.w += h2f(u4.w);
  }
  float4 xx = *(const float4*)(x + (size_t)i * DDIM + d0);
  float4 o;
  o.x = acc.x * inv + xx.x;
  o.y = acc.y * inv + xx.y;
  o.z = acc.z * inv + xx.z;
  o.w = acc.w * inv + xx.w;
  *(float4*)(out + (size_t)i * DDIM + d0) = o;
}

extern "C" void kernel_launch(void* const* d_in, const int* in_sizes, int n_in,
                              void* d_out, int out_size, void* d_ws, size_t ws_size,
                              hipStream_t stream)
{
  const float* x  = (const float*)d_in[0];
  const float* Wq = (const float*)d_in[1];
  const float* bq = (const float*)d_in[2];
  const float* Wk = (const float*)d_in[3];
  const float* bk = (const float*)d_in[4];
  const float* Wv = (const float*)d_in[5];
  const float* bv = (const float*)d_in[6];

  char* ws = (char*)d_ws;
  unsigned short* xp   = (unsigned short*)(ws + 0);          // 4 MB (fragment-packed x)
  unsigned short* Wp   = (unsigned short*)(ws + 4194304);    // 384 KB (fragment-packed W)
  unsigned short* qb   = (unsigned short*)(ws + 4587520);    // 4 MB
  unsigned short* kb   = (unsigned short*)(ws + 8781824);    // 4 MB
  unsigned short* vtp  = (unsigned short*)(ws + 12976128);   // 4 MB (staged-order V)
  unsigned short* nump = (unsigned short*)(ws + 17170432);   // 16 MB (4 splits, fp16)
  float* denp = (float*)(ws + 33947648);                     // 256 KB (8 slices)

  convert_kernel<<<1120, 256, 0, stream>>>(x, Wq, Wk, Wv, xp, Wp);
  qkv_kernel<<<384, 256, 0, stream>>>(bq, bk, bv, xp, Wp, qb, kb, vtp);
  attn_kernel<<<(NROWS / BM) * KSPLIT, 1024, 0, stream>>>(qb, kb, vtp, nump, denp);
  combine_kernel<<<NROWS / 4, 256, 0, stream>>>(x, nump, denp, (float*)d_out);
}

// Round 16
// 121.710 us; speedup vs baseline: 1.0662x; 1.0027x over previous
//
#include <hip/hip_runtime.h>

#define NROWS 8192
#define DDIM  256
#define KSPLIT 4
#define BM 128
#define BK 64
#define NT (NROWS / KSPLIT / BK)   // 32 tiles per split

typedef __bf16 bf16x8 __attribute__((ext_vector_type(8)));
typedef float  f32x4  __attribute__((ext_vector_type(4)));
typedef float  f32x16 __attribute__((ext_vector_type(16)));

typedef __attribute__((address_space(1))) unsigned int uint_gas;
typedef __attribute__((address_space(3))) unsigned int uint_las;

__device__ __forceinline__ void gload_lds16(const void* g, void* l) {
  __builtin_amdgcn_global_load_lds((const uint_gas*)g, (uint_las*)l, 16, 0, 0);
}

__device__ __forceinline__ unsigned int f2bf_bits(float f) {
  union { float f; unsigned int u; } v; v.f = f;
  unsigned int r = v.u + 0x7FFFu + ((v.u >> 16) & 1u);
  return r >> 16;
}
__device__ __forceinline__ float bf2f(unsigned int b) {
  union { unsigned int u; float f; } v; v.u = b << 16;
  return v.f;
}
__device__ __forceinline__ unsigned int pack2bf(float a, float b) {
  union { unsigned int u; __bf16 h[2]; } p;
  p.h[0] = (__bf16)a; p.h[1] = (__bf16)b;
  return p.u;
}
__device__ __forceinline__ unsigned short f2h_bits(float f) {
  union { _Float16 h; unsigned short u; } c; c.h = (_Float16)f;
  return c.u;
}
__device__ __forceinline__ float h2f(unsigned short u) {
  union { unsigned short u; _Float16 h; } c; c.u = u;
  return (float)c.h;
}

// ---------------- kernel 0: fp32 -> bf16, MFMA-fragment-order packing ----------------
#define NXFRAG (512 * 8 * 64)        // 262144
#define NWFRAG (3 * 16 * 8 * 64)     // 24576
__global__ __launch_bounds__(256) void convert_kernel(
    const float* __restrict__ x, const float* __restrict__ wq,
    const float* __restrict__ wk, const float* __restrict__ wv,
    unsigned short* __restrict__ xp, unsigned short* __restrict__ Wp)
{
  int tid = blockIdx.x * 256 + threadIdx.x;
  const float* src;
  unsigned short* dst;
  int row, col;
  if (tid < NXFRAG) {
    int l = tid & 63, ks = (tid >> 6) & 7, rt = tid >> 9;
    src = x; dst = xp + (size_t)tid * 8;
    row = rt * 16 + (l & 15); col = ks * 32 + (l >> 4) * 8;
  } else {
    int fid = tid - NXFRAG;
    if (fid >= NWFRAG) return;
    int l = fid & 63, ks = (fid >> 6) & 7, ct = (fid >> 9) & 15, out = fid >> 13;
    src = (out == 0) ? wq : (out == 1) ? wk : wv;
    dst = Wp + (size_t)fid * 8;
    row = ct * 16 + (l & 15); col = ks * 32 + (l >> 4) * 8;
  }
  const float* p = src + (size_t)row * DDIM + col;
  float4 f0 = *(const float4*)p;
  float4 f1 = *(const float4*)(p + 4);
  ushort4 o0, o1;
  o0.x = (unsigned short)f2bf_bits(f0.x); o0.y = (unsigned short)f2bf_bits(f0.y);
  o0.z = (unsigned short)f2bf_bits(f0.z); o0.w = (unsigned short)f2bf_bits(f0.w);
  o1.x = (unsigned short)f2bf_bits(f1.x); o1.y = (unsigned short)f2bf_bits(f1.y);
  o1.z = (unsigned short)f2bf_bits(f1.z); o1.w = (unsigned short)f2bf_bits(f1.w);
  *(ushort4*)dst = o0;
  *(ushort4*)(dst + 4) = o1;
}

// ---------------- kernel 1: QKV projections + L2 norm + vtp (staged-order V) ----------------
// vtp layout per 64-k window: [window 128][blk=d/32 (8)][s=k16B (8)][d&31][16B]
__global__ __launch_bounds__(256) void qkv_kernel(
    const float* __restrict__ bq, const float* __restrict__ bk, const float* __restrict__ bv,
    const unsigned short* __restrict__ xp, const unsigned short* __restrict__ Wp,
    unsigned short* __restrict__ qb, unsigned short* __restrict__ kb,
    unsigned short* __restrict__ vtp)
{
  __shared__ unsigned short vstage[DDIM * 72];
  const int t = threadIdx.x;
  const int w = t >> 6, l = t & 63;
  const int c = l & 15, g = l >> 4;
  const int out = blockIdx.x / 128;
  const int mb  = blockIdx.x % 128;
  const int row0 = mb * 64;
  const int rw = row0 + w * 16;
  const int rt = mb * 4 + w;           // global 16-row tile id

  bf16x8 a[8];
  #pragma unroll
  for (int ks = 0; ks < 8; ks++)
    a[ks] = *(const bf16x8*)(xp + ((size_t)(rt * 8 + ks) * 64 + l) * 8);

  const float* bias = (out == 0) ? bq : (out == 1) ? bk : bv;
  f32x4 vals[16];
  #pragma unroll
  for (int ct = 0; ct < 16; ct++) {
    f32x4 acc = {0.f, 0.f, 0.f, 0.f};
    #pragma unroll
    for (int ks = 0; ks < 8; ks++) {
      bf16x8 b = *(const bf16x8*)(Wp + ((size_t)((out * 16 + ct) * 8 + ks) * 64 + l) * 8);
      acc = __builtin_amdgcn_mfma_f32_16x16x32_bf16(a[ks], b, acc, 0, 0, 0);
    }
    float bias_v = bias[ct * 16 + c];
    #pragma unroll
    for (int r = 0; r < 4; r++) acc[r] += bias_v;
    vals[ct] = acc;
  }
  if (out < 2) {   // L2 normalize rows (q, k)
    #pragma unroll
    for (int r = 0; r < 4; r++) {
      float ss = 0.f;
      #pragma unroll
      for (int ct = 0; ct < 16; ct++) ss += vals[ct][r] * vals[ct][r];
      ss += __shfl_xor(ss, 1); ss += __shfl_xor(ss, 2);
      ss += __shfl_xor(ss, 4); ss += __shfl_xor(ss, 8);
      float inv = 1.f / fmaxf(sqrtf(ss), 1e-12f);
      #pragma unroll
      for (int ct = 0; ct < 16; ct++) vals[ct][r] *= inv;
    }
    unsigned short* dst = (out == 0) ? qb : kb;
    #pragma unroll
    for (int ct = 0; ct < 16; ct++) {
      #pragma unroll
      for (int r = 0; r < 4; r++) {
        unsigned int bits = f2bf_bits(vals[ct][r]);
        unsigned int ob = (unsigned int)__shfl_xor((int)bits, 1);
        if (!(l & 1))
          *(unsigned int*)(dst + (size_t)(rw + g * 4 + r) * DDIM + ct * 16 + c) =
              bits | (ob << 16);
      }
    }
  } else {
    #pragma unroll
    for (int ct = 0; ct < 16; ct++)
      #pragma unroll
      for (int r = 0; r < 4; r++)
        vstage[(ct * 16 + c) * 72 + (w * 16 + g * 4 + r)] =
            (unsigned short)f2bf_bits(vals[ct][r]);
    __syncthreads();
    // write staged-order image: chunk n -> (blk = n>>8, s = (n>>5)&7, d31 = n&31)
    unsigned short* wdst = vtp + (size_t)mb * 16384;
    #pragma unroll
    for (int p = 0; p < 8; p++) {
      int n = p * 256 + t;
      int dg = ((n >> 8) << 5) + (n & 31);   // d row 0..255
      int s  = (n >> 5) & 7;
      *(uint4*)(wdst + (size_t)n * 8) = *(const uint4*)(vstage + dg * 72 + s * 8);
    }
  }
}

// ---------------- kernel 2: fused relu-attention, producer-consumer waves ----------------
// 16 waves @ 4/SIMD. S-waves (0-7): qa hoisted, S^T=K.Q^T, pack P->Pb[cur] slot-major,
// stage K (LDS), diag under uniform guard, den. PV-waves (8-15): V loaded DIRECT
// global->register (vtp pre-packed, 512B-contiguous per 32 lanes), ping-pong reg sets
// vfrA/vfrB with one-full-iteration latency cover; pre-barrier drain is lgkmcnt-ONLY
// (no vmem drain on PV path — V loads span barriers). LDS = 2xK(64K) + 2xP(32K) = 96KB.
__global__ __launch_bounds__(1024, 4) void attn_kernel(
    const unsigned short* __restrict__ qb, const unsigned short* __restrict__ kb,
    const unsigned short* __restrict__ vtp,
    unsigned short* __restrict__ nump, float* __restrict__ denp)
{
  __shared__ __align__(16) char smem[98304];
  char* kbuf = smem;            // [2][32768]
  char* Pb   = smem + 65536;    // [2][16384]

  const int t = threadIdx.x;
  const int w = t >> 6, l = t & 63;
  const int l31 = l & 31, hi = l >> 5;
  const int rw = w & 7;          // role-local wave id
  const int ts = t & 511;        // role-local thread id
  const int bid = blockIdx.x;
  const int split = bid & (KSPLIT - 1);
  const int mb = bid >> 2;
  const int q0 = mb * BM;
  const int kbase0 = split * (NROWS / KSPLIT);
  const char* kbc = (const char*)kb;
  const char* vtc = (const char*)vtp;

  if (w < 8) {
    // ===================== PRODUCER: S-waves =====================
    const int sr = rw >> 1, sc = rw & 1;
    const int qrow = sr * 32 + l31;
    const int qrowg = q0 + qrow;
    const int krl = sc * 32 + l31;

    bf16x8 qa[16];
    {
      const unsigned short* qrowp = qb + (size_t)(q0 + qrow) * DDIM + hi * 8;
      #pragma unroll
      for (int m = 0; m < 16; m++) qa[m] = *(const bf16x8*)(qrowp + m * 16);
    }
    float denl = 0.f;

    auto stageK = [&](int buf, int it) {
      const char* ksrc = kbc + (size_t)(kbase0 + it * BK) * 512;
      #pragma unroll
      for (int i = 0; i < 4; i++) {
        int n = i * 512 + ts;
        int row = n >> 5, slot = n & 31;
        // rotation swizzle: lds[row][slot] = K[row][(slot-row)&31]
        gload_lds16(ksrc + row * 512 + (((slot - row) & 31) << 4),
                    kbuf + buf * 32768 + i * 8192 + rw * 1024);
      }
    };

    stageK(0, 0);
    asm volatile("s_waitcnt vmcnt(0)" ::: "memory");
    __builtin_amdgcn_sched_barrier(0);
    __builtin_amdgcn_s_barrier();           // prologue barrier
    __builtin_amdgcn_sched_barrier(0);

    for (int it = 0; it < NT; ++it) {
      const int cur = it & 1;
      if (it + 1 < NT) stageK(cur ^ 1, it + 1);
      __builtin_amdgcn_sched_barrier(0);

      const char* kcur = kbuf + cur * 32768;
      f32x16 sacc = (f32x16){0.f};
      #pragma unroll
      for (int m = 0; m < 16; m++) {
        bf16x8 kf = *(const bf16x8*)(kcur + krl * 512 +
                                     (((m * 2 + hi + krl) & 31) << 4));
        sacc = __builtin_amdgcn_mfma_f32_32x32x16_bf16(kf, qa[m], sacc, 0, 0, 0);
      }
      // P pack: slot-major — byte = sr*4096 + (sc*4+q)*512 + l31*16 + hi*8
      char* pbase = Pb + cur * 16384 + sr * 4096 + l31 * 16 + hi * 8;
      const int kbase = kbase0 + it * BK;
      if (__builtin_expect(kbase < q0 + BM && q0 < kbase + BK, 0)) {
        // cold path (~2% of tiles): per-lane diag zeroing via ternaries
        const int dref = qrowg - (kbase + sc * 32 + hi * 4);
        #pragma unroll
        for (int q = 0; q < 4; q++) {
          float v0 = fmaxf(sacc[4 * q + 0], 0.f);
          float v1 = fmaxf(sacc[4 * q + 1], 0.f);
          float v2 = fmaxf(sacc[4 * q + 2], 0.f);
          float v3 = fmaxf(sacc[4 * q + 3], 0.f);
          const int d = dref - 8 * q;
          v0 = (d == 0) ? 0.f : v0;
          v1 = (d == 1) ? 0.f : v1;
          v2 = (d == 2) ? 0.f : v2;
          v3 = (d == 3) ? 0.f : v3;
          denl += (v0 + v1) + (v2 + v3);
          uint2 d2;
          d2.x = pack2bf(v0, v1);
          d2.y = pack2bf(v2, v3);
          *(uint2*)(pbase + (sc * 4 + q) * 512) = d2;
        }
      } else {
        // hot path: branch-free pack
        #pragma unroll
        for (int q = 0; q < 4; q++) {
          float v0 = fmaxf(sacc[4 * q + 0], 0.f);
          float v1 = fmaxf(sacc[4 * q + 1], 0.f);
          float v2 = fmaxf(sacc[4 * q + 2], 0.f);
          float v3 = fmaxf(sacc[4 * q + 3], 0.f);
          denl += (v0 + v1) + (v2 + v3);
          uint2 d2;
          d2.x = pack2bf(v0, v1);
          d2.y = pack2bf(v2, v3);
          *(uint2*)(pbase + (sc * 4 + q) * 512) = d2;
        }
      }
      asm volatile("s_waitcnt vmcnt(0) lgkmcnt(0)" ::: "memory");
      __builtin_amdgcn_sched_barrier(0);
      __builtin_amdgcn_s_barrier();
      __builtin_amdgcn_sched_barrier(0);
    }

    // den: lanes l and l+32 hold the same qrow's two kcol interleaves
    float d = denl;
    d += __shfl_xor(d, 32);
    if (l < 32)
      denp[((size_t)split * 2 + sc) * NROWS + q0 + sr * 32 + l] = d;
  } else {
    // ===================== CONSUMER: PV-waves =====================
    const int pr = rw >> 2, pc = rw & 3;

    f32x16 oacc[2][2];
    #pragma unroll
    for (int rt = 0; rt < 2; rt++)
      #pragma unroll
      for (int dt = 0; dt < 2; dt++)
        oacc[rt][dt] = (f32x16){0.f};

    bf16x8 vfrA[8], vfrB[8];

    auto loadV = [&](bf16x8 (&dst)[8], int it) {
      const char* vsrc = vtc + (size_t)((kbase0 + it * BK) >> 6) * 32768;
      #pragma unroll
      for (int ch = 0; ch < 4; ch++)
        #pragma unroll
        for (int dt = 0; dt < 2; dt++)
          dst[ch * 2 + dt] = *(const bf16x8*)(vsrc + (pc * 2 + dt) * 4096 +
                                              (ch * 2 + hi) * 512 + l31 * 16);
    };
    auto pvcomp = [&](const bf16x8 (&vfr)[8], const char* Pprev) {
      #pragma unroll
      for (int ch = 0; ch < 4; ch++) {
        const int s512 = (ch * 2 + hi) * 512 + l31 * 16;
        bf16x8 pa0 = *(const bf16x8*)(Pprev + (pr * 2 + 0) * 4096 + s512);
        bf16x8 pa1 = *(const bf16x8*)(Pprev + (pr * 2 + 1) * 4096 + s512);
        #pragma unroll
        for (int dt = 0; dt < 2; dt++) {
          oacc[0][dt] = __builtin_amdgcn_mfma_f32_32x32x16_bf16(pa0, vfr[ch * 2 + dt],
                                                                oacc[0][dt], 0, 0, 0);
          oacc[1][dt] = __builtin_amdgcn_mfma_f32_32x32x16_bf16(pa1, vfr[ch * 2 + dt],
                                                                oacc[1][dt], 0, 0, 0);
        }
      }
    };

    __builtin_amdgcn_s_barrier();           // prologue barrier (match producer)
    __builtin_amdgcn_sched_barrier(0);

    for (int it2 = 0; it2 < NT; it2 += 2) {
      // ---- even iter (it = it2, cur = 0): load A <- V(it2), compute PV(it2-1) from B
      loadV(vfrA, it2);
      if (it2 > 0) pvcomp(vfrB, Pb + 16384);
      asm volatile("s_waitcnt lgkmcnt(0)" ::: "memory");
      __builtin_amdgcn_sched_barrier(0);
      __builtin_amdgcn_s_barrier();
      __builtin_amdgcn_sched_barrier(0);
      // ---- odd iter (it = it2+1, cur = 1): load B <- V(it2+1), compute PV(it2) from A
      loadV(vfrB, it2 + 1);
      pvcomp(vfrA, Pb + 0);
      asm volatile("s_waitcnt lgkmcnt(0)" ::: "memory");
      __builtin_amdgcn_sched_barrier(0);
      __builtin_amdgcn_s_barrier();
      __builtin_amdgcn_sched_barrier(0);
    }
    // epilogue: PV(NT-1) consumes vfrB (loaded at it = NT-1), P in Pb[1]
    pvcomp(vfrB, Pb + 16384);

    // write numerator partials (fp16). C layout: col=lane&31, row=(r&3)+8*(r>>2)+4*hi
    unsigned short* np = nump + (size_t)split * NROWS * DDIM;
    #pragma unroll
    for (int rt = 0; rt < 2; rt++)
      #pragma unroll
      for (int dt = 0; dt < 2; dt++)
        #pragma unroll
        for (int r = 0; r < 16; r++) {
          int rowg = q0 + pr * 64 + rt * 32 + (r & 3) + 8 * (r >> 2) + 4 * hi;
          int col  = pc * 64 + dt * 32 + l31;
          np[(size_t)rowg * DDIM + col] = f2h_bits(oacc[rt][dt][r]);
        }
  }
}

// ---------------- kernel 3: combine partials (pure streaming) ----------------
__global__ __launch_bounds__(256) void combine_kernel(
    const float* __restrict__ x,
    const unsigned short* __restrict__ nump, const float* __restrict__ denp,
    float* __restrict__ out)
{
  const int t = threadIdx.x;
  const int w = t >> 6, l = t & 63;
  const int i = blockIdx.x * 4 + w;

  float den = 0.f;
  #pragma unroll
  for (int sp = 0; sp < KSPLIT * 2; sp++)
    den += denp[(size_t)sp * NROWS + i];
  float inv = 1.f / fmaxf(den, 1e-12f);

  const int d0 = l * 4;
  float4 acc = {0.f, 0.f, 0.f, 0.f};
  #pragma unroll
  for (int sp = 0; sp < KSPLIT; sp++) {
    ushort4 u4 = *(const ushort4*)(nump + ((size_t)sp * NROWS + i) * DDIM + d0);
    acc.x += h2f(u4.x); acc.y += h2f(u4.y);
    acc.z += h2f(u4.z); acc.w += h2f(u4.w);
  }
  float4 xx = *(const float4*)(x + (size_t)i * DDIM + d0);
  float4 o;
  o.x = acc.x * inv + xx.x;
  o.y = acc.y * inv + xx.y;
  o.z = acc.z * inv + xx.z;
  o.w = acc.w * inv + xx.w;
  *(float4*)(out + (size_t)i * DDIM + d0) = o;
}

extern "C" void kernel_launch(void* const* d_in, const int* in_sizes, int n_in,
                              void* d_out, int out_size, void* d_ws, size_t ws_size,
                              hipStream_t stream)
{
  const float* x  = (const float*)d_in[0];
  const float* Wq = (const float*)d_in[1];
  const float* bq = (const float*)d_in[2];
  const float* Wk = (const float*)d_in[3];
  const float* bk = (const float*)d_in[4];
  const float* Wv = (const float*)d_in[5];
  const float* bv = (const float*)d_in[6];

  char* ws = (char*)d_ws;
  unsigned short* xp   = (unsigned short*)(ws + 0);          // 4 MB (fragment-packed x)
  unsigned short* Wp   = (unsigned short*)(ws + 4194304);    // 384 KB (fragment-packed W)
  unsigned short* qb   = (unsigned short*)(ws + 4587520);    // 4 MB
  unsigned short* kb   = (unsigned short*)(ws + 8781824);    // 4 MB
  unsigned short* vtp  = (unsigned short*)(ws + 12976128);   // 4 MB (staged-order V)
  unsigned short* nump = (unsigned short*)(ws + 17170432);   // 16 MB (4 splits, fp16)
  float* denp = (float*)(ws + 33947648);                     // 256 KB (8 slices)

  convert_kernel<<<1120, 256, 0, stream>>>(x, Wq, Wk, Wv, xp, Wp);
  qkv_kernel<<<384, 256, 0, stream>>>(bq, bk, bv, xp, Wp, qb, kb, vtp);
  attn_kernel<<<(NROWS / BM) * KSPLIT, 1024, 0, stream>>>(qb, kb, vtp, nump, denp);
  combine_kernel<<<NROWS / 4, 256, 0, stream>>>(x, nump, denp, (float*)d_out);
}